// Round 1
// 692.820 us; speedup vs baseline: 1.1184x; 1.1184x over previous
//
#include <hip/hip_runtime.h>
#include <math.h>

// Problem constants (fixed by setup_inputs)
#define BB 8
#define NN 2048
#define HH 128
#define NSEG 8             // j-segments per node (256 j's each)
#define SEGJ 256
#define SEGCAP 12          // capacity per segment (Poisson mean ~1.1/seg)
#define MAXNBR (NSEG*SEGCAP)  // 96 per node
#define PREDL 10
#define TSTRIDE (NN*3)
#define OUT_BSTRIDE ((PREDL+1)*NN*3)

// R15 (polish session): two bit-identical restructurings of k_mid/k_last:
//  (a) GEMM remap 1 node x 8 cols -> 2 nodes x 4 cols: 6 ds_read_b128 per
//      32 fmas instead of 9 (-33% LDS issue), per-output fmaf chain still
//      k-ascending 0..127 -> bit-identical.
//  (b) gather chunk-4 software pipeline: 8 independent float4 loads in
//      flight instead of a serial j->load->add chain; add order preserved.
// k_adj / k_l0 GEMM / FC head untouched. absmax must stay 0.03125 exactly.

// ---------------------------------------------------------------------------
// K0: states0 = [points, 0]; write t=0 output slice
// ---------------------------------------------------------------------------
__global__ __launch_bounds__(256) void k_init(const float* __restrict__ points,
                                              float* __restrict__ states,
                                              float* __restrict__ out) {
    int idx = blockIdx.x * 256 + threadIdx.x;
    if (idx >= BB * NN) return;
    int b = idx >> 11;
    int n = idx & 2047;
    float px = points[idx * 3 + 0];
    float py = points[idx * 3 + 1];
    float pz = points[idx * 3 + 2];
    float* s = states + (size_t)idx * 6;
    s[0] = px; s[1] = py; s[2] = pz; s[3] = 0.f; s[4] = 0.f; s[5] = 0.f;
    float* o = out + (size_t)b * OUT_BSTRIDE + n * 3;
    o[0] = px; o[1] = py; o[2] = pz;
}

// ---------------------------------------------------------------------------
// K1: radius-graph (verbatim R10, bit-exact verified). 256 blocks x 512 thr;
// wave = one seg x 64 nodes -> pos[j] is ONE LDS address per wave.
// ---------------------------------------------------------------------------
__global__ __launch_bounds__(512, 2) void k_adj(const float* __restrict__ states,
                                                float* __restrict__ xs0,
                                                float* __restrict__ dinv,
                                                int* __restrict__ nbr,
                                                int* __restrict__ cntN) {
    const float R2c = 0.01f;
    int b = blockIdx.x & 7;
    int tile = blockIdx.x >> 3;     // 0..31 (64 nodes each)
    __shared__ float4 pos[NN];                  // 32 KiB
    __shared__ int degs[512];                   // 2 KiB
    __shared__ unsigned short jb[512][SEGCAP];  // 12 KiB
    const float* sb = states + (size_t)b * NN * 6;
    for (int j = threadIdx.x; j < NN; j += 512) {
        const float* r = sb + j * 6;
        pos[j] = make_float4(r[0], r[1], r[2], 0.f);
    }
    __syncthreads();
    int node = threadIdx.x & 63;
    int seg  = threadIdx.x >> 6;     // 0..7 == wave id
    int i = tile * 64 + node;
    int gi = b * NN + i;
    float4 pi = pos[i];
    int cnt = 0;
    int j0 = seg * SEGJ;
#pragma unroll 4
    for (int j = j0; j < j0 + SEGJ; ++j) {
        float4 pj = pos[j];
        float dx = pi.x - pj.x;
        float dy = pi.y - pj.y;
        float dz = pi.z - pj.z;
        // exact np order: (dx*dx + dy*dy) + dz*dz, each op rounded, no fma
        float d2 = __fadd_rn(__fadd_rn(__fmul_rn(dx, dx), __fmul_rn(dy, dy)),
                             __fmul_rn(dz, dz));
        if (d2 < R2c && j != i) {
            if (cnt < SEGCAP) jb[threadIdx.x][cnt] = (unsigned short)j;
            cnt++;
        }
    }
    if (cnt > SEGCAP) cnt = SEGCAP;
    degs[threadIdx.x] = cnt;        // tid == seg*64 + node
    __syncthreads();
    int off = 0;
    for (int s = 0; s < seg; ++s) off += degs[s * 64 + node];
    int base = gi * MAXNBR + off;
    for (int k = 0; k < cnt; ++k) nbr[base + k] = (int)jb[threadIdx.x][k];
    if (seg == NSEG - 1) {
        int tot = off + cnt;
        cntN[gi] = tot;
        float di = (float)(1.0 / sqrt((double)(1 + tot)));  // exact rsqrt
        dinv[gi] = di;
        const float* srow = sb + (size_t)i * 6;
        float* xr = xs0 + (size_t)gi * 6;
#pragma unroll
        for (int c = 0; c < 6; ++c) xr[c] = di * srow[c];
    }
}

// ---------------------------------------------------------------------------
// K2: layer 0 (6 -> 128). 512 blocks x 512 thr: 32 nodes x 16 parts (8 ch).
// Same per-output fmaf order (k ascending) -> bit-identical.
// Gather pipelined in chunks of 4 neighbors (add order preserved).
// ---------------------------------------------------------------------------
__global__ __launch_bounds__(512, 4) void k_l0(const float* __restrict__ xs0,
                                               const float* __restrict__ dinv,
                                               const int* __restrict__ nbr,
                                               const int* __restrict__ cntN,
                                               const float* __restrict__ W0,
                                               const float* __restrict__ b0,
                                               float* __restrict__ xs1) {
    int b = blockIdx.x & 7;
    int tile = blockIdx.x >> 3;
    int node = threadIdx.x >> 4;   // 0..31
    int part = threadIdx.x & 15;   // 8 ch each
    int i = tile * 32 + node;
    int gi = b * NN + i;
    float g[6];
    {
        const float* sr = xs0 + (size_t)gi * 6;
        float2 a0 = *(const float2*)sr;
        float2 a1 = *(const float2*)(sr + 2);
        float2 a2 = *(const float2*)(sr + 4);
        g[0] = a0.x; g[1] = a0.y; g[2] = a1.x; g[3] = a1.y; g[4] = a2.x; g[5] = a2.y;
    }
    int cnt = cntN[gi];
    const int* nb = nbr + gi * MAXNBR;
    const float* xb = xs0 + (size_t)b * NN * 6;
    int k = 0;
    for (; k + 4 <= cnt; k += 4) {
        const float* r0 = xb + (size_t)nb[k]     * 6;
        const float* r1 = xb + (size_t)nb[k + 1] * 6;
        const float* r2 = xb + (size_t)nb[k + 2] * 6;
        const float* r3 = xb + (size_t)nb[k + 3] * 6;
        float2 v00 = *(const float2*)r0, v01 = *(const float2*)(r0 + 2), v02 = *(const float2*)(r0 + 4);
        float2 v10 = *(const float2*)r1, v11 = *(const float2*)(r1 + 2), v12 = *(const float2*)(r1 + 4);
        float2 v20 = *(const float2*)r2, v21 = *(const float2*)(r2 + 2), v22 = *(const float2*)(r2 + 4);
        float2 v30 = *(const float2*)r3, v31 = *(const float2*)(r3 + 2), v32 = *(const float2*)(r3 + 4);
        g[0] += v00.x; g[1] += v00.y; g[2] += v01.x; g[3] += v01.y; g[4] += v02.x; g[5] += v02.y;
        g[0] += v10.x; g[1] += v10.y; g[2] += v11.x; g[3] += v11.y; g[4] += v12.x; g[5] += v12.y;
        g[0] += v20.x; g[1] += v20.y; g[2] += v21.x; g[3] += v21.y; g[4] += v22.x; g[5] += v22.y;
        g[0] += v30.x; g[1] += v30.y; g[2] += v31.x; g[3] += v31.y; g[4] += v32.x; g[5] += v32.y;
    }
    for (; k < cnt; ++k) {
        int j = nb[k];
        const float* xr = xb + (size_t)j * 6;
        float2 v0 = *(const float2*)xr;
        float2 v1 = *(const float2*)(xr + 2);
        float2 v2 = *(const float2*)(xr + 4);
        g[0] += v0.x; g[1] += v0.y; g[2] += v1.x;
        g[3] += v1.y; g[4] += v2.x; g[5] += v2.y;
    }
    float di = dinv[gi];
#pragma unroll
    for (int c = 0; c < 6; ++c) g[c] *= di;
    int c0 = part * 8;
    float y[8];
#pragma unroll
    for (int r = 0; r < 2; ++r) {
        float4 bv = *(const float4*)(b0 + c0 + r * 4);
        y[r * 4 + 0] = bv.x; y[r * 4 + 1] = bv.y; y[r * 4 + 2] = bv.z; y[r * 4 + 3] = bv.w;
    }
#pragma unroll
    for (int kk = 0; kk < 6; ++kk) {
        float u = g[kk];
        const float* wr = W0 + kk * HH + c0;
#pragma unroll
        for (int r = 0; r < 2; ++r) {
            float4 w = *(const float4*)(wr + r * 4);
            y[r * 4 + 0] = fmaf(u, w.x, y[r * 4 + 0]);
            y[r * 4 + 1] = fmaf(u, w.y, y[r * 4 + 1]);
            y[r * 4 + 2] = fmaf(u, w.z, y[r * 4 + 2]);
            y[r * 4 + 3] = fmaf(u, w.w, y[r * 4 + 3]);
        }
    }
    float* xo = xs1 + (size_t)gi * HH + c0;
#pragma unroll
    for (int r = 0; r < 2; ++r) {
        float4 v;
        v.x = di * fmaxf(y[r * 4 + 0], 0.f);
        v.y = di * fmaxf(y[r * 4 + 1], 0.f);
        v.z = di * fmaxf(y[r * 4 + 2], 0.f);
        v.w = di * fmaxf(y[r * 4 + 3], 0.f);
        *(float4*)(xo + r * 4) = v;
    }
}

// ---------------------------------------------------------------------------
// 128->128 layers: 512 blocks x 512 thr, 32-node tiles, 16 waves/CU.
// Gather: thread = (node = t>>4, part = t&15, 8 ch), chunk-4 pipelined.
// GEMM: thread = 2 nodes x 4 cols (W float4 shared by both nodes).
// ---------------------------------------------------------------------------
__device__ __forceinline__ void gather_into_lds(const float* __restrict__ xin,
                                                const float* __restrict__ dinv,
                                                const int* __restrict__ nbr,
                                                const int* __restrict__ cntN,
                                                int b, int tile,
                                                float (*uS)[HH + 4]) {
    const int node = threadIdx.x >> 4;   // 0..31
    const int part = threadIdx.x & 15;   // 8 ch each
    const int i = tile * 32 + node;
    const int gi = b * NN + i;
    const int c0 = part * 8;
    float acc[8];
    const float* xs = xin + (size_t)gi * HH + c0;
#pragma unroll
    for (int r = 0; r < 2; ++r) *(float4*)&acc[r * 4] = *(const float4*)(xs + r * 4);
    const int cnt = cntN[gi];
    const int* nb = nbr + gi * MAXNBR;
    const float* xb = xin + (size_t)b * NN * HH + c0;
    int k = 0;
    for (; k + 4 <= cnt; k += 4) {
        const float* r0 = xb + (size_t)nb[k]     * HH;
        const float* r1 = xb + (size_t)nb[k + 1] * HH;
        const float* r2 = xb + (size_t)nb[k + 2] * HH;
        const float* r3 = xb + (size_t)nb[k + 3] * HH;
        float4 a0 = *(const float4*)r0, b0 = *(const float4*)(r0 + 4);
        float4 a1 = *(const float4*)r1, b1 = *(const float4*)(r1 + 4);
        float4 a2 = *(const float4*)r2, b2 = *(const float4*)(r2 + 4);
        float4 a3 = *(const float4*)r3, b3 = *(const float4*)(r3 + 4);
        acc[0] += a0.x; acc[1] += a0.y; acc[2] += a0.z; acc[3] += a0.w;
        acc[4] += b0.x; acc[5] += b0.y; acc[6] += b0.z; acc[7] += b0.w;
        acc[0] += a1.x; acc[1] += a1.y; acc[2] += a1.z; acc[3] += a1.w;
        acc[4] += b1.x; acc[5] += b1.y; acc[6] += b1.z; acc[7] += b1.w;
        acc[0] += a2.x; acc[1] += a2.y; acc[2] += a2.z; acc[3] += a2.w;
        acc[4] += b2.x; acc[5] += b2.y; acc[6] += b2.z; acc[7] += b2.w;
        acc[0] += a3.x; acc[1] += a3.y; acc[2] += a3.z; acc[3] += a3.w;
        acc[4] += b3.x; acc[5] += b3.y; acc[6] += b3.z; acc[7] += b3.w;
    }
    for (; k < cnt; ++k) {
        const int j = nb[k];
        const float* xr = xb + (size_t)j * HH;
#pragma unroll
        for (int r = 0; r < 2; ++r) {
            float v[4];
            *(float4*)v = *(const float4*)(xr + r * 4);
            acc[r * 4 + 0] += v[0]; acc[r * 4 + 1] += v[1];
            acc[r * 4 + 2] += v[2]; acc[r * 4 + 3] += v[3];
        }
    }
    const float di = dinv[gi];
#pragma unroll
    for (int r = 0; r < 2; ++r) {
        float4 o;
        o.x = acc[r * 4 + 0] * di; o.y = acc[r * 4 + 1] * di;
        o.z = acc[r * 4 + 2] * di; o.w = acc[r * 4 + 3] * di;
        *(float4*)&uS[node][c0 + r * 4] = o;
    }
}

// GEMM over one 32-row W panel in LDS. Thread owns 2 nodes x 4 channels
// {cA..cA+3}; one W float4 feeds both nodes. Per-output k-ascending fmaf
// order -> bit-identical to the 1x8 mapping.
__device__ __forceinline__ void gemm_panel2(const float (*uS)[HH + 4],
                                            const float* __restrict__ wbuf,
                                            int p, int n0, int n1, int cA,
                                            float y0[4], float y1[4]) {
#pragma unroll 2
    for (int r = 0; r < 32; r += 4) {
        float ua[4], ub[4];
        *(float4*)ua = *(const float4*)(&uS[n0][p * 32 + r]);
        *(float4*)ub = *(const float4*)(&uS[n1][p * 32 + r]);
        const float* wrow = wbuf + r * HH + cA;
#pragma unroll
        for (int q = 0; q < 4; ++q) {
            float4 w = *(const float4*)(wrow + q * HH);
            float u0 = ua[q], u1 = ub[q];
            y0[0] = fmaf(u0, w.x, y0[0]); y0[1] = fmaf(u0, w.y, y0[1]);
            y0[2] = fmaf(u0, w.z, y0[2]); y0[3] = fmaf(u0, w.w, y0[3]);
            y1[0] = fmaf(u1, w.x, y1[0]); y1[1] = fmaf(u1, w.y, y1[1]);
            y1[2] = fmaf(u1, w.z, y1[2]); y1[3] = fmaf(u1, w.w, y1[3]);
        }
    }
}

// K3: middle layer (layer 1): xs_out = dinv * relu(u @ W + b)
__global__ __launch_bounds__(512, 4) void k_mid(const float* __restrict__ xin,
                                                const float* __restrict__ dinv,
                                                const int* __restrict__ nbr,
                                                const int* __restrict__ cntN,
                                                const float* __restrict__ W,
                                                const float* __restrict__ bias,
                                                float* __restrict__ xout) {
    __shared__ __align__(16) float uS[32][HH + 4];   // 16.9 KB
    __shared__ __align__(16) float wS[2][32 * HH];   // 32 KB
    int b = blockIdx.x & 7;
    int tile = blockIdx.x >> 3;
    int t = threadIdx.x;
    const float4* Wf4 = (const float4*)W;
    float4 wreg[2];
    wreg[0] = Wf4[t]; wreg[1] = Wf4[t + 512];   // panel 0
    gather_into_lds(xin, dinv, nbr, cntN, b, tile, uS);
    {
        float4* ws4 = (float4*)wS[0];
        ws4[t] = wreg[0]; ws4[t + 512] = wreg[1];
    }
    __syncthreads();
    int cb = t & 31, np = t >> 5;
    int cA = cb * 4;
    int n0 = np * 2, n1 = np * 2 + 1;
    float y0[4], y1[4];
    {
        float4 bv = *(const float4*)(bias + cA);
        y0[0] = bv.x; y0[1] = bv.y; y0[2] = bv.z; y0[3] = bv.w;
        y1[0] = bv.x; y1[1] = bv.y; y1[2] = bv.z; y1[3] = bv.w;
    }
#pragma unroll
    for (int p = 0; p < 4; ++p) {
        if (p < 3) {
            wreg[0] = Wf4[(p + 1) * 1024 + t];
            wreg[1] = Wf4[(p + 1) * 1024 + t + 512];
        }
        gemm_panel2(uS, wS[p & 1], p, n0, n1, cA, y0, y1);
        if (p < 3) {
            float4* ws4 = (float4*)wS[1 - (p & 1)];
            ws4[t] = wreg[0]; ws4[t + 512] = wreg[1];
            __syncthreads();
        }
    }
    int g0 = b * NN + tile * 32 + n0;
    int g1 = g0 + 1;
    float di0 = dinv[g0];
    float di1 = dinv[g1];
    float* o0 = xout + (size_t)g0 * HH + cA;
    float* o1 = xout + (size_t)g1 * HH + cA;
    float4 va, vb;
    va.x = di0 * fmaxf(y0[0], 0.f); va.y = di0 * fmaxf(y0[1], 0.f);
    va.z = di0 * fmaxf(y0[2], 0.f); va.w = di0 * fmaxf(y0[3], 0.f);
    vb.x = di1 * fmaxf(y1[0], 0.f); vb.y = di1 * fmaxf(y1[1], 0.f);
    vb.z = di1 * fmaxf(y1[2], 0.f); vb.w = di1 * fmaxf(y1[3], 0.f);
    *(float4*)o0 = va; *(float4*)o1 = vb;
}

// K4: layer 2 + FC head + state update + output write.
// After the last panel, wS[0] is reused as y3[32][128] and wS[1] as wfcS.
__global__ __launch_bounds__(512, 4) void k_last(const float* __restrict__ xin,
                                                 const float* __restrict__ dinv,
                                                 const int* __restrict__ nbr,
                                                 const int* __restrict__ cntN,
                                                 const float* __restrict__ W2,
                                                 const float* __restrict__ b2,
                                                 const float* __restrict__ Wfc,
                                                 const float* __restrict__ bfc,
                                                 const float* __restrict__ padding,
                                                 float* __restrict__ states,
                                                 float* __restrict__ outt) {
    __shared__ __align__(16) float uS[32][HH + 4];   // 16.9 KB
    __shared__ __align__(16) float wS[2][32 * HH];   // 32 KB
    int b = blockIdx.x & 7;
    int tile = blockIdx.x >> 3;
    int t = threadIdx.x;
    const float4* Wf4 = (const float4*)W2;
    float4 wreg[2];
    wreg[0] = Wf4[t]; wreg[1] = Wf4[t + 512];
    gather_into_lds(xin, dinv, nbr, cntN, b, tile, uS);
    {
        float4* ws4 = (float4*)wS[0];
        ws4[t] = wreg[0]; ws4[t + 512] = wreg[1];
    }
    __syncthreads();
    int cb = t & 31, np = t >> 5;
    int cA = cb * 4;
    int n0 = np * 2, n1 = np * 2 + 1;
    float y0[4], y1[4];
    {
        float4 bv = *(const float4*)(b2 + cA);
        y0[0] = bv.x; y0[1] = bv.y; y0[2] = bv.z; y0[3] = bv.w;
        y1[0] = bv.x; y1[1] = bv.y; y1[2] = bv.z; y1[3] = bv.w;
    }
#pragma unroll
    for (int p = 0; p < 4; ++p) {
        if (p < 3) {
            wreg[0] = Wf4[(p + 1) * 1024 + t];
            wreg[1] = Wf4[(p + 1) * 1024 + t + 512];
        }
        gemm_panel2(uS, wS[p & 1], p, n0, n1, cA, y0, y1);
        if (p < 3) {
            float4* ws4 = (float4*)wS[1 - (p & 1)];
            ws4[t] = wreg[0]; ws4[t + 512] = wreg[1];
            __syncthreads();
        }
    }
    __syncthreads();   // all panel reads done; reuse wS
    float* y3  = wS[0];   // [32][HH]
    float* wfc = wS[1];   // HH*6 floats
    for (int q = t; q < HH * 6; q += 512) wfc[q] = Wfc[q];
    {
        float4 v;
        v.x = fmaxf(y0[0], 0.f); v.y = fmaxf(y0[1], 0.f);
        v.z = fmaxf(y0[2], 0.f); v.w = fmaxf(y0[3], 0.f);
        *(float4*)&y3[n0 * HH + cA] = v;
        v.x = fmaxf(y1[0], 0.f); v.y = fmaxf(y1[1], 0.f);
        v.z = fmaxf(y1[2], 0.f); v.w = fmaxf(y1[3], 0.f);
        *(float4*)&y3[n1 * HH + cA] = v;
    }
    __syncthreads();
    if (t < 192) {
        int n = t / 6;
        int c = t - n * 6;
        float r = bfc[c];
        for (int k = 0; k < HH; k += 4) {
            float yv[4];
            *(float4*)yv = *(const float4*)&y3[n * HH + k];
            r = fmaf(yv[0], wfc[(k + 0) * 6 + c], r);
            r = fmaf(yv[1], wfc[(k + 1) * 6 + c], r);
            r = fmaf(yv[2], wfc[(k + 2) * 6 + c], r);
            r = fmaf(yv[3], wfc[(k + 3) * 6 + c], r);
        }
        int i = tile * 32 + n;
        int gi = b * NN + i;
        float pv = padding[b * NN + i];   // all-ones in this setup
        float s = states[(size_t)gi * 6 + c] + r * pv;
        states[(size_t)gi * 6 + c] = s;
        if (c < 3) outt[(size_t)b * OUT_BSTRIDE + i * 3 + c] = s;
    }
}

// ---------------------------------------------------------------------------
extern "C" void kernel_launch(void* const* d_in, const int* in_sizes, int n_in,
                              void* d_out, int out_size, void* d_ws, size_t ws_size,
                              hipStream_t stream) {
    (void)in_sizes; (void)n_in; (void)out_size; (void)ws_size;
    const float* points  = (const float*)d_in[0];
    const float* padding = (const float*)d_in[5];
    const float* W0  = (const float*)d_in[6];
    const float* b0  = (const float*)d_in[7];
    const float* W1  = (const float*)d_in[8];
    const float* b1  = (const float*)d_in[9];
    const float* W2  = (const float*)d_in[10];
    const float* b2  = (const float*)d_in[11];
    const float* Wfc = (const float*)d_in[12];
    const float* bfc = (const float*)d_in[13];
    float* out = (float*)d_out;

    // workspace carve-up (~24 MB)
    float* ws     = (float*)d_ws;
    float* states = ws;                       // BB*NN*6
    float* xs0    = states + BB * NN * 6;     // BB*NN*6
    float* xs1    = xs0 + BB * NN * 6;        // BB*NN*HH
    float* xs2    = xs1 + BB * NN * HH;       // BB*NN*HH
    float* dinvp  = xs2 + BB * NN * HH;       // BB*NN
    int*   nbr    = (int*)(dinvp + BB * NN);  // BB*NN*MAXNBR
    int*   cntN   = nbr + BB * NN * MAXNBR;   // BB*NN

    k_init<<<(BB * NN) / 256, 256, 0, stream>>>(points, states, out);
    for (int t = 0; t < PREDL; ++t) {
        k_adj<<<256, 512, 0, stream>>>(states, xs0, dinvp, nbr, cntN);
        k_l0<<<512, 512, 0, stream>>>(xs0, dinvp, nbr, cntN, W0, b0, xs1);
        k_mid<<<512, 512, 0, stream>>>(xs1, dinvp, nbr, cntN, W1, b1, xs2);
        k_last<<<512, 512, 0, stream>>>(xs2, dinvp, nbr, cntN, W2, b2, Wfc, bfc,
                                        padding, states,
                                        out + (size_t)(t + 1) * TSTRIDE);
    }
}